// Round 2
// baseline (1745.829 us; speedup 1.0000x reference)
//
#include <hip/hip_runtime.h>

// VQ-VAE quantizer: x[B=128, C=256, H=32, W=32] fp32, e[K=512, C=256] fp32.
// out[b,c,hw] = e[argmin_k ||z_{b,hw} - e_k||^2][c].
//
// Strategy: fp32 pass computes scores s_k = ||e_k||^2 - 2 z.e_k (||z||^2 is
// row-constant) with best + second-best tracking. Rows whose fp32 gap is
// below EPS (10x the fp32 worst-case comparison error) go to a worklist and
// are re-resolved exactly in fp64 by a follow-up kernel (one wave per row),
// which rewrites that output row. Expected flagged rows ~400 of 131072.

constexpr int K_EMB = 512;
constexpr int C_DIM = 256;
constexpr int HW    = 1024;   // 32*32
constexpr int TK    = 64;     // k-tile (64 fp32 accumulators/thread)
constexpr int CC    = 4;      // c-chunk
constexpr float EPS_GAP = 0.03125f;

// ws layout (bytes): [0,4) job counter | [1024, 3072) ebias f32[512] | [4096, ...) worklist int[]
constexpr size_t WS_EBIAS_OFF = 1024;
constexpr size_t WS_WORK_OFF  = 4096;

__global__ __launch_bounds__(256) void ebias_kernel(const float* __restrict__ e,
                                                    float* __restrict__ ebias,
                                                    int* __restrict__ count) {
    int k = blockIdx.x * 256 + threadIdx.x;
    if (blockIdx.x == 0 && threadIdx.x == 0) *count = 0;
    if (k >= K_EMB) return;
    const float4* row = reinterpret_cast<const float4*>(e + (size_t)k * C_DIM);
    double s = 0.0;
#pragma unroll
    for (int i = 0; i < C_DIM / 4; ++i) {
        float4 v = row[i];
        s = fma((double)v.x, (double)v.x, s);
        s = fma((double)v.y, (double)v.y, s);
        s = fma((double)v.z, (double)v.z, s);
        s = fma((double)v.w, (double)v.w, s);
    }
    ebias[k] = (float)s;
}

// One thread per spatial position; 256 threads = 256 consecutive hw positions
// of one image. e/ebias indices are wave-uniform -> scalar (SGPR) loads.
__global__ __launch_bounds__(256) void vq_kernel(const float* __restrict__ x,
                                                 const float* __restrict__ e,
                                                 const float* __restrict__ ebias,
                                                 float* __restrict__ out,
                                                 int* __restrict__ count,
                                                 int* __restrict__ worklist,
                                                 int maxjobs) {
    const int b  = blockIdx.x >> 2;
    const int hw = ((blockIdx.x & 3) << 8) + threadIdx.x;
    const float* xb = x + (size_t)b * C_DIM * HW + hw;   // x[b,c,hw] = xb[c*HW]

    float best = 1e30f, second = 1e30f;
    int   bidx = 0;

    for (int k0 = 0; k0 < K_EMB; k0 += TK) {
        float acc[TK];
#pragma unroll
        for (int i = 0; i < TK; ++i) acc[i] = 0.f;

#pragma unroll 1
        for (int c0 = 0; c0 < C_DIM; c0 += CC) {
            float z[CC];
#pragma unroll
            for (int cc = 0; cc < CC; ++cc) z[cc] = xb[(size_t)(c0 + cc) * HW];
#pragma unroll
            for (int kk = 0; kk < TK; ++kk) {
                const float* er = e + (size_t)(k0 + kk) * C_DIM + c0;  // uniform
#pragma unroll
                for (int cc = 0; cc < CC; ++cc)
                    acc[kk] = fmaf(z[cc], er[cc], acc[kk]);
            }
        }

#pragma unroll
        for (int kk = 0; kk < TK; ++kk) {
            float score = ebias[k0 + kk] - 2.f * acc[kk];
            if (score < best) { second = best; best = score; bidx = k0 + kk; }
            else if (score < second) { second = score; }
        }
    }

    // Near-tie -> exact fp64 re-resolution later.
    if (second - best < EPS_GAP) {
        int slot = atomicAdd(count, 1);
        if (slot < maxjobs) worklist[slot] = blockIdx.x * 256 + threadIdx.x;  // row id
    }

    // out[b,c,hw] = e[bidx][c]
    float* ob = out + (size_t)b * C_DIM * HW + hw;
    const float4* er = reinterpret_cast<const float4*>(e + (size_t)bidx * C_DIM);
#pragma unroll 1
    for (int c4 = 0; c4 < C_DIM / 4; ++c4) {
        float4 v = er[c4];
        ob[(size_t)(c4 * 4 + 0) * HW] = v.x;
        ob[(size_t)(c4 * 4 + 1) * HW] = v.y;
        ob[(size_t)(c4 * 4 + 2) * HW] = v.z;
        ob[(size_t)(c4 * 4 + 3) * HW] = v.w;
    }
}

// One wave (64 threads) per flagged row: exact fp64 argmin over all 512
// codes (d = sum (z-e)^2, ~1e-13 relative error), first-index tie-break,
// rewrite the output row.
__global__ __launch_bounds__(64) void refine_kernel(const float* __restrict__ x,
                                                    const float* __restrict__ e,
                                                    float* __restrict__ out,
                                                    const int* __restrict__ worklist,
                                                    const int* __restrict__ count,
                                                    int maxjobs) {
    int njobs = *count;
    if (njobs > maxjobs) njobs = maxjobs;
    const int lane = threadIdx.x;

    for (int job = blockIdx.x; job < njobs; job += gridDim.x) {
        const int row = worklist[job];
        const int b  = row >> 10;
        const int hw = row & (HW - 1);
        const float* xb = x + (size_t)b * C_DIM * HW + hw;

        double bestd = 1e300;
        int    besti = K_EMB;
        for (int k = lane; k < K_EMB; k += 64) {
            const float* er = e + (size_t)k * C_DIM;
            double d = 0.0;
            for (int c = 0; c < C_DIM; ++c) {
                double diff = (double)xb[(size_t)c * HW] - (double)er[c];
                d = fma(diff, diff, d);
            }
            if (d < bestd || (d == bestd && k < besti)) { bestd = d; besti = k; }
        }
        // wave-level lexicographic min-reduce (64 lanes)
        for (int off = 32; off > 0; off >>= 1) {
            double od = __shfl_down(bestd, off);
            int    oi = __shfl_down(besti, off);
            if (od < bestd || (od == bestd && oi < besti)) { bestd = od; besti = oi; }
        }
        besti = __shfl(besti, 0);

        // rewrite out row: 64 lanes x float4 covers C=256
        const float4 v = reinterpret_cast<const float4*>(e + (size_t)besti * C_DIM)[lane];
        float* ob = out + (size_t)b * C_DIM * HW + hw;
        ob[(size_t)(lane * 4 + 0) * HW] = v.x;
        ob[(size_t)(lane * 4 + 1) * HW] = v.y;
        ob[(size_t)(lane * 4 + 2) * HW] = v.z;
        ob[(size_t)(lane * 4 + 3) * HW] = v.w;
    }
}

extern "C" void kernel_launch(void* const* d_in, const int* in_sizes, int n_in,
                              void* d_out, int out_size, void* d_ws, size_t ws_size,
                              hipStream_t stream) {
    const float* x = (const float*)d_in[0];
    const float* e = (const float*)d_in[1];
    float* out = (float*)d_out;

    char* ws = (char*)d_ws;
    int*   count = (int*)ws;
    float* ebias = (float*)(ws + WS_EBIAS_OFF);
    int*   worklist = (int*)(ws + WS_WORK_OFF);
    int maxjobs = 0;
    if (ws_size > WS_WORK_OFF + 4)
        maxjobs = (int)(((ws_size - WS_WORK_OFF) / 4 > 65536) ? 65536
                                                              : (ws_size - WS_WORK_OFF) / 4);

    const int B = in_sizes[0] / (C_DIM * HW);

    hipLaunchKernelGGL(ebias_kernel, dim3((K_EMB + 255) / 256), dim3(256), 0, stream,
                       e, ebias, count);
    hipLaunchKernelGGL(vq_kernel, dim3(B * (HW / 256)), dim3(256), 0, stream,
                       x, e, ebias, out, count, worklist, maxjobs);
    hipLaunchKernelGGL(refine_kernel, dim3(512), dim3(64), 0, stream,
                       x, e, out, worklist, count, maxjobs);
}

// Round 3
// 830.965 us; speedup vs baseline: 2.1010x; 2.1010x over previous
//
#include <hip/hip_runtime.h>

// VQ-VAE quantizer: x[B=128, C=256, H=32, W=32] fp32, e[K=512, C=256] fp32.
// out[b,c,hw] = e[argmin_k ||z_{b,hw} - e_k||^2][c].
//
// Fast fp32 pass: score_k = ||e_k||^2 - 2 z.e_k with best/second tracking;
// near-ties (gap < EPS) are re-resolved exactly in fp64 by refine_kernel.
//
// Register plan (the R2 failure was compiler-restructured accumulators):
//   - acc[TK=32] fp32 in VGPRs (small enough to never spill/AGPR)
//   - e read via e^T [C][K] (precomputed in ws) so each c-step's 32 values
//     are contiguous -> 4x s_load_dwordx16 on the scalar pipe (uniform)
//   - z (per-lane) double-buffered vector loads, FMA = v_fmac_f32 v,s,v

constexpr int K_EMB = 512;
constexpr int C_DIM = 256;
constexpr int HW    = 1024;   // 32*32
constexpr int TK    = 32;     // k-tile: 32 fp32 accumulators/thread
constexpr float EPS_GAP = 0.03125f;

// ws layout (bytes):
//   [0,4)            job counter
//   [1024, 3072)     ebias f32[512]
//   [4096, 528384)   eT f32[C_DIM][K_EMB]  (512 KB)
//   [528384, ...)    worklist int[]
constexpr size_t WS_EBIAS_OFF = 1024;
constexpr size_t WS_ET_OFF    = 4096;
constexpr size_t WS_WORK_OFF  = WS_ET_OFF + (size_t)C_DIM * K_EMB * 4;

__global__ __launch_bounds__(256) void ebias_kernel(const float* __restrict__ e,
                                                    float* __restrict__ ebias,
                                                    int* __restrict__ count) {
    int k = blockIdx.x * 256 + threadIdx.x;
    if (blockIdx.x == 0 && threadIdx.x == 0) *count = 0;
    if (k >= K_EMB) return;
    const float4* row = reinterpret_cast<const float4*>(e + (size_t)k * C_DIM);
    double s = 0.0;
#pragma unroll
    for (int i = 0; i < C_DIM / 4; ++i) {
        float4 v = row[i];
        s = fma((double)v.x, (double)v.x, s);
        s = fma((double)v.y, (double)v.y, s);
        s = fma((double)v.z, (double)v.z, s);
        s = fma((double)v.w, (double)v.w, s);
    }
    ebias[k] = (float)s;
}

// eT[c][k] = e[k][c]; 512 KB once per call, trivial cost.
__global__ __launch_bounds__(256) void etrans_kernel(const float* __restrict__ e,
                                                     float* __restrict__ eT) {
    const int k = blockIdx.x;        // 512 blocks
    const int c = threadIdx.x;       // 256 threads, coalesced read of e row
    eT[(size_t)c * K_EMB + k] = e[(size_t)k * C_DIM + c];
}

__global__ __launch_bounds__(256) void vq_kernel(const float* __restrict__ x,
                                                 const float* __restrict__ eT,
                                                 const float* __restrict__ e,
                                                 const float* __restrict__ ebias,
                                                 float* __restrict__ out,
                                                 int* __restrict__ count,
                                                 int* __restrict__ worklist,
                                                 int maxjobs) {
    const int b  = blockIdx.x >> 2;
    const int hw = ((blockIdx.x & 3) << 8) + threadIdx.x;
    const float* xb = x + (size_t)b * C_DIM * HW + hw;   // x[b,c,hw] = xb[c*HW]

    float best = 1e30f, second = 1e30f;
    int   bidx = 0;

#pragma unroll 1
    for (int k0 = 0; k0 < K_EMB; k0 += TK) {
        float acc[TK];
#pragma unroll
        for (int i = 0; i < TK; ++i) acc[i] = 0.f;

        // z double-buffer: load pair c0+2,c0+3 while FMA-ing pair c0,c0+1
        float zb0 = xb[0];
        float zb1 = xb[HW];

#pragma unroll 1
        for (int c0 = 0; c0 < C_DIM; c0 += 2) {
            const float z0 = zb0;
            const float z1 = zb1;
            if (c0 + 2 < C_DIM) {
                zb0 = xb[(size_t)(c0 + 2) * HW];
                zb1 = xb[(size_t)(c0 + 3) * HW];
            }
            // 2 x 32 contiguous uniform floats -> 4x s_load_dwordx16
            const float* e0 = eT + (size_t)(c0 + 0) * K_EMB + k0;
            const float* e1 = eT + (size_t)(c0 + 1) * K_EMB + k0;
#pragma unroll
            for (int kk = 0; kk < TK; ++kk)
                acc[kk] = fmaf(z0, e0[kk], acc[kk]);
#pragma unroll
            for (int kk = 0; kk < TK; ++kk)
                acc[kk] = fmaf(z1, e1[kk], acc[kk]);
        }

#pragma unroll
        for (int kk = 0; kk < TK; ++kk) {
            float score = ebias[k0 + kk] - 2.f * acc[kk];   // uniform scalar load
            if (score < best) { second = best; best = score; bidx = k0 + kk; }
            else if (score < second) { second = score; }
        }
    }

    // Near-tie -> exact fp64 re-resolution later.
    if (second - best < EPS_GAP) {
        int slot = atomicAdd(count, 1);
        if (slot < maxjobs) worklist[slot] = blockIdx.x * 256 + threadIdx.x;
    }

    // out[b,c,hw] = e[bidx][c]
    float* ob = out + (size_t)b * C_DIM * HW + hw;
    const float4* er = reinterpret_cast<const float4*>(e + (size_t)bidx * C_DIM);
#pragma unroll 1
    for (int c4 = 0; c4 < C_DIM / 4; ++c4) {
        float4 v = er[c4];
        ob[(size_t)(c4 * 4 + 0) * HW] = v.x;
        ob[(size_t)(c4 * 4 + 1) * HW] = v.y;
        ob[(size_t)(c4 * 4 + 2) * HW] = v.z;
        ob[(size_t)(c4 * 4 + 3) * HW] = v.w;
    }
}

// One wave per flagged row: exact fp64 argmin over all 512 codes, first-index
// tie-break, rewrite the output row.
__global__ __launch_bounds__(64) void refine_kernel(const float* __restrict__ x,
                                                    const float* __restrict__ e,
                                                    float* __restrict__ out,
                                                    const int* __restrict__ worklist,
                                                    const int* __restrict__ count,
                                                    int maxjobs) {
    int njobs = *count;
    if (njobs > maxjobs) njobs = maxjobs;
    const int lane = threadIdx.x;

    for (int job = blockIdx.x; job < njobs; job += gridDim.x) {
        const int row = worklist[job];
        const int b  = row >> 10;
        const int hw = row & (HW - 1);
        const float* xb = x + (size_t)b * C_DIM * HW + hw;

        double bestd = 1e300;
        int    besti = K_EMB;
        for (int k = lane; k < K_EMB; k += 64) {
            const float* er = e + (size_t)k * C_DIM;
            double d = 0.0;
            for (int c = 0; c < C_DIM; ++c) {
                double diff = (double)xb[(size_t)c * HW] - (double)er[c];
                d = fma(diff, diff, d);
            }
            if (d < bestd || (d == bestd && k < besti)) { bestd = d; besti = k; }
        }
        for (int off = 32; off > 0; off >>= 1) {
            double od = __shfl_down(bestd, off);
            int    oi = __shfl_down(besti, off);
            if (od < bestd || (od == bestd && oi < besti)) { bestd = od; besti = oi; }
        }
        besti = __shfl(besti, 0);

        const float4 v = reinterpret_cast<const float4*>(e + (size_t)besti * C_DIM)[lane];
        float* ob = out + (size_t)b * C_DIM * HW + hw;
        ob[(size_t)(lane * 4 + 0) * HW] = v.x;
        ob[(size_t)(lane * 4 + 1) * HW] = v.y;
        ob[(size_t)(lane * 4 + 2) * HW] = v.z;
        ob[(size_t)(lane * 4 + 3) * HW] = v.w;
    }
}

extern "C" void kernel_launch(void* const* d_in, const int* in_sizes, int n_in,
                              void* d_out, int out_size, void* d_ws, size_t ws_size,
                              hipStream_t stream) {
    const float* x = (const float*)d_in[0];
    const float* e = (const float*)d_in[1];
    float* out = (float*)d_out;

    char* ws = (char*)d_ws;
    int*   count = (int*)ws;
    float* ebias = (float*)(ws + WS_EBIAS_OFF);
    float* eT    = (float*)(ws + WS_ET_OFF);
    int*   worklist = (int*)(ws + WS_WORK_OFF);
    int maxjobs = 0;
    if (ws_size > WS_WORK_OFF + 4) {
        size_t avail = (ws_size - WS_WORK_OFF) / 4;
        maxjobs = (int)(avail > 65536 ? 65536 : avail);
    }

    const int B = in_sizes[0] / (C_DIM * HW);

    hipLaunchKernelGGL(ebias_kernel, dim3((K_EMB + 255) / 256), dim3(256), 0, stream,
                       e, ebias, count);
    hipLaunchKernelGGL(etrans_kernel, dim3(K_EMB), dim3(256), 0, stream, e, eT);
    hipLaunchKernelGGL(vq_kernel, dim3(B * (HW / 256)), dim3(256), 0, stream,
                       x, eT, e, ebias, out, count, worklist, maxjobs);
    hipLaunchKernelGGL(refine_kernel, dim3(512), dim3(64), 0, stream,
                       x, e, out, worklist, count, maxjobs);
}

// Round 4
// 278.805 us; speedup vs baseline: 6.2618x; 2.9805x over previous
//
#include <hip/hip_runtime.h>

// VQ-VAE quantizer via MFMA: x[B=128,C=256,H=32,W=32] f32, e[K=512,C=256] f32.
// out[b,c,hw] = e[argmin_k ||z - e_k||^2][c].
//
// score_k = ||e_k||^2 - 2 z.e_k  (||z||^2 row-constant). The dot is a
// [131072 x 256] x [256 x 512] GEMM -> bf16 MFMA with Dekker split:
//   z = zh + zl, e = eh + el;  z.e ~= zh.eh + zl.eh + zh.el   (err ~1e-3)
// Near-ties (gap < EPS=0.02) re-resolved exactly in fp64 by refine_kernel.

typedef __attribute__((ext_vector_type(8))) short bf16x8;
typedef __attribute__((ext_vector_type(4))) float f32x4;

constexpr int K_EMB = 512;
constexpr int C_DIM = 256;
constexpr int HW    = 1024;
constexpr float EPS_GAP = 0.02f;

// ws layout (bytes)
constexpr size_t WS_EBIAS = 64;                    // f32[512]
constexpr size_t WS_EH    = 4096;                  // bf16 bits [512][256] = 256KB
constexpr size_t WS_EL    = WS_EH + 262144;        // 256KB
constexpr size_t WS_IDX   = WS_EL + 262144;        // int[131072] = 512KB
constexpr size_t WS_WORK  = WS_IDX + 524288;       // worklist

__device__ __forceinline__ unsigned short f2bf(float f) {
    unsigned u = __float_as_uint(f);
    return (unsigned short)((u + 0x7FFFu + ((u >> 16) & 1u)) >> 16);
}

// ---- prep: e -> (eH, eL) bf16 planes + exact ebias, zero job counter ----
__global__ __launch_bounds__(256) void prep_e(const float* __restrict__ e,
                                              unsigned short* __restrict__ eH,
                                              unsigned short* __restrict__ eL,
                                              float* __restrict__ ebias,
                                              int* __restrict__ count) {
    const int k = blockIdx.x, c = threadIdx.x;
    if (k == 0 && c == 0) *count = 0;
    float v = e[(size_t)k * C_DIM + c];
    unsigned short h = f2bf(v);
    float hf = __uint_as_float(((unsigned)h) << 16);
    unsigned short l = f2bf(v - hf);
    eH[(size_t)k * C_DIM + c] = h;
    eL[(size_t)k * C_DIM + c] = l;

    __shared__ double red[256];
    red[c] = (double)v * (double)v;
    __syncthreads();
    for (int s = 128; s > 0; s >>= 1) {
        if (c < s) red[c] += red[c + s];
        __syncthreads();
    }
    if (c == 0) ebias[k] = (float)red[0];
}

// ---- stage one 16-code tile (hi+lo planes, 16KB) into LDS, swizzled ----
// LDS linear layout written by global_load_lds (lane*16 contiguous); the
// bank-conflict swizzle (byte ^= (row&15)<<4) is applied on the GLOBAL source
// address (G21: both-sides-or-neither), readers apply the same XOR.
__device__ __forceinline__ void stage_tile(char* smem, int buf, int nt, int w, int lane,
                                           const unsigned short* eH,
                                           const unsigned short* eL) {
#pragma unroll
    for (int s = 0; s < 4; ++s) {
        int q = w * 4 + s;            // 0..15 across the block
        int plane = q >> 3;           // 0 = hi, 1 = lo
        int ip = q & 7;               // 1KB chunk within plane (8KB = 16 rows x 512B)
        int row = ip * 2 + (lane >> 5);
        int co  = (lane & 31) * 16;   // byte offset within row
        const unsigned short* src = (plane ? eL : eH)
            + ((size_t)(nt * 16 + row)) * C_DIM + ((co ^ ((row & 15) << 4)) >> 1);
        char* dst = smem + buf * 16384 + plane * 8192 + ip * 1024;  // wave-uniform
        __builtin_amdgcn_global_load_lds(
            (const __attribute__((address_space(1))) unsigned int*)src,
            (__attribute__((address_space(3))) unsigned int*)dst, 16, 0, 0);
    }
}

// ---- main: GEMM + in-register argmin ----
// Block = 4 waves = 128 rows (consecutive hw of one image). Wave: 32 rows as
// two 16-row m-frags. A (z) built in-register from x (read once, coalesced
// 64B segments); B (e) from swizzled LDS tiles, double-buffered.
__global__ __launch_bounds__(256, 2) void vq_mfma(const float* __restrict__ x,
                                                  const unsigned short* __restrict__ eH,
                                                  const unsigned short* __restrict__ eL,
                                                  const float* __restrict__ ebias,
                                                  int* __restrict__ idx_out,
                                                  int* __restrict__ count,
                                                  int* __restrict__ worklist,
                                                  int maxjobs) {
    __shared__ __align__(16) char smem[32768];
    const int t = threadIdx.x, lane = t & 63, w = t >> 6;
    const int b = blockIdx.x >> 3;
    const int hw0 = (blockIdx.x & 7) << 7;
    const float* xb = x + (size_t)b * C_DIM * HW;

    // A fragments: lane holds A[m = lane&15][k = 8*(lane>>4) + j], j=0..7
    bf16x8 Ah[2][8], Al[2][8];
#pragma unroll
    for (int mf = 0; mf < 2; ++mf) {
        const int hw = hw0 + w * 32 + mf * 16 + (lane & 15);
#pragma unroll
        for (int cs = 0; cs < 8; ++cs) {
#pragma unroll
            for (int j = 0; j < 8; ++j) {
                int c = cs * 32 + ((lane >> 4) << 3) + j;
                float v = xb[(size_t)c * HW + hw];
                unsigned short h = f2bf(v);
                float hf = __uint_as_float(((unsigned)h) << 16);
                unsigned short l = f2bf(v - hf);
                Ah[mf][cs][j] = (short)h;
                Al[mf][cs][j] = (short)l;
            }
        }
    }

    float best[8], second[8];
    int bidx[8];
#pragma unroll
    for (int s = 0; s < 8; ++s) { best[s] = 1e30f; second[s] = 1e30f; bidx[s] = 0; }

    // per-lane swizzled LDS read base: row = lane&15 (code), co = (lane>>4)*16
    const int bro = (lane & 15) * 512 + ((((lane >> 4) << 4)) ^ ((lane & 15) << 4));

    stage_tile(smem, 0, 0, w, lane, eH, eL);
    __syncthreads();

    for (int nt = 0; nt < 32; ++nt) {
        const int cur = nt & 1;
        if (nt < 31) stage_tile(smem, cur ^ 1, nt + 1, w, lane, eH, eL);

        const char* base = smem + cur * 16384;
        f32x4 acc0 = {0.f, 0.f, 0.f, 0.f}, acc1 = {0.f, 0.f, 0.f, 0.f};
#pragma unroll
        for (int cs = 0; cs < 8; ++cs) {
            int off = bro ^ (cs << 6);   // XOR-composable: co bits disjoint
            bf16x8 Bh = *reinterpret_cast<const bf16x8*>(base + off);
            bf16x8 Bl = *reinterpret_cast<const bf16x8*>(base + 8192 + off);
            acc0 = __builtin_amdgcn_mfma_f32_16x16x32_bf16(Ah[0][cs], Bh, acc0, 0, 0, 0);
            acc1 = __builtin_amdgcn_mfma_f32_16x16x32_bf16(Ah[1][cs], Bh, acc1, 0, 0, 0);
            acc0 = __builtin_amdgcn_mfma_f32_16x16x32_bf16(Al[0][cs], Bh, acc0, 0, 0, 0);
            acc1 = __builtin_amdgcn_mfma_f32_16x16x32_bf16(Al[1][cs], Bh, acc1, 0, 0, 0);
            acc0 = __builtin_amdgcn_mfma_f32_16x16x32_bf16(Ah[0][cs], Bl, acc0, 0, 0, 0);
            acc1 = __builtin_amdgcn_mfma_f32_16x16x32_bf16(Ah[1][cs], Bl, acc1, 0, 0, 0);
        }

        float eb = ebias[nt * 16 + (lane & 15)];
        int code = nt * 16 + (lane & 15);
#pragma unroll
        for (int mf = 0; mf < 2; ++mf) {
#pragma unroll
            for (int r = 0; r < 4; ++r) {
                float sc = fmaf(-2.f, (mf ? acc1[r] : acc0[r]), eb);
                int slot = mf * 4 + r;
                if (sc < best[slot]) { second[slot] = best[slot]; best[slot] = sc; bidx[slot] = code; }
                else second[slot] = fminf(second[slot], sc);
            }
        }
        __syncthreads();
    }

    // butterfly argmin over the 16 col-lanes (keep true top-2, first-idx ties)
#pragma unroll
    for (int m = 1; m < 16; m <<= 1) {
#pragma unroll
        for (int s = 0; s < 8; ++s) {
            float ob = __shfl_xor(best[s], m);
            float os = __shfl_xor(second[s], m);
            int   oi = __shfl_xor(bidx[s], m);
            bool take = (ob < best[s]) || (ob == best[s] && oi < bidx[s]);
            float ns = take ? fminf(best[s], os) : fminf(second[s], ob);
            if (take) { best[s] = ob; bidx[s] = oi; }
            second[s] = ns;
        }
    }

    if ((lane & 15) == 0) {
#pragma unroll
        for (int s = 0; s < 8; ++s) {
            int row_local = (s >> 2) * 16 + ((lane >> 4) << 2) + (s & 3);
            int n = blockIdx.x * 128 + w * 32 + row_local;
            idx_out[n] = bidx[s];
            if (second[s] - best[s] < EPS_GAP) {
                int sl = atomicAdd(count, 1);
                if (sl < maxjobs) worklist[sl] = n;
            }
        }
    }
}

// ---- gather: out[b,c,hw] = e[idx[n]][c]; stores coalesced, e rows via L1 ----
__global__ __launch_bounds__(256) void gather_out(const float* __restrict__ e,
                                                  const int* __restrict__ idx,
                                                  float* __restrict__ out) {
    const int b = blockIdx.x >> 3;
    const int hw0 = (blockIdx.x & 7) << 7;
    const int t = threadIdx.x;
    __shared__ int widx[128];
    if (t < 128) widx[t] = idx[(size_t)b * HW + hw0 + t];
    __syncthreads();
#pragma unroll
    for (int jh = 0; jh < 2; ++jh) {
        int j = jh * 64 + (t & 63);
        const float* er = e + (size_t)widx[j] * C_DIM;
        float* ob = out + (size_t)b * C_DIM * HW + hw0 + j;
#pragma unroll 4
        for (int it = 0; it < 64; ++it) {
            int c = it * 4 + (t >> 6);
            ob[(size_t)c * HW] = er[c];
        }
    }
}

// ---- refine: exact fp64 argmin for flagged rows, rewrite out row ----
__global__ __launch_bounds__(64) void refine_kernel(const float* __restrict__ x,
                                                    const float* __restrict__ e,
                                                    float* __restrict__ out,
                                                    const int* __restrict__ worklist,
                                                    const int* __restrict__ count,
                                                    int maxjobs) {
    int njobs = *count;
    if (njobs > maxjobs) njobs = maxjobs;
    const int lane = threadIdx.x;

    for (int job = blockIdx.x; job < njobs; job += gridDim.x) {
        const int row = worklist[job];
        const int b = row >> 10;
        const int hw = row & (HW - 1);
        const float* xb = x + (size_t)b * C_DIM * HW + hw;

        double bestd = 1e300;
        int besti = K_EMB;
        for (int k = lane; k < K_EMB; k += 64) {
            const float* er = e + (size_t)k * C_DIM;
            double d = 0.0;
            for (int c = 0; c < C_DIM; ++c) {
                double diff = (double)xb[(size_t)c * HW] - (double)er[c];
                d = fma(diff, diff, d);
            }
            if (d < bestd || (d == bestd && k < besti)) { bestd = d; besti = k; }
        }
        for (int off = 32; off > 0; off >>= 1) {
            double od = __shfl_down(bestd, off);
            int    oi = __shfl_down(besti, off);
            if (od < bestd || (od == bestd && oi < besti)) { bestd = od; besti = oi; }
        }
        besti = __shfl(besti, 0);

        const float4 v = reinterpret_cast<const float4*>(e + (size_t)besti * C_DIM)[lane];
        float* ob = out + (size_t)b * C_DIM * HW + hw;
        ob[(size_t)(lane * 4 + 0) * HW] = v.x;
        ob[(size_t)(lane * 4 + 1) * HW] = v.y;
        ob[(size_t)(lane * 4 + 2) * HW] = v.z;
        ob[(size_t)(lane * 4 + 3) * HW] = v.w;
    }
}

extern "C" void kernel_launch(void* const* d_in, const int* in_sizes, int n_in,
                              void* d_out, int out_size, void* d_ws, size_t ws_size,
                              hipStream_t stream) {
    const float* x = (const float*)d_in[0];
    const float* e = (const float*)d_in[1];
    float* out = (float*)d_out;

    char* ws = (char*)d_ws;
    int* count = (int*)ws;
    float* ebias = (float*)(ws + WS_EBIAS);
    unsigned short* eH = (unsigned short*)(ws + WS_EH);
    unsigned short* eL = (unsigned short*)(ws + WS_EL);
    int* idx = (int*)(ws + WS_IDX);
    int* worklist = (int*)(ws + WS_WORK);
    int maxjobs = 0;
    if (ws_size > WS_WORK + 4) {
        size_t avail = (ws_size - WS_WORK) / 4;
        maxjobs = (int)(avail > 65536 ? 65536 : avail);
    }

    const int B = in_sizes[0] / (C_DIM * HW);

    hipLaunchKernelGGL(prep_e, dim3(K_EMB), dim3(256), 0, stream, e, eH, eL, ebias, count);
    hipLaunchKernelGGL(vq_mfma, dim3(B * 8), dim3(256), 0, stream,
                       x, eH, eL, ebias, idx, count, worklist, maxjobs);
    hipLaunchKernelGGL(gather_out, dim3(B * 8), dim3(256), 0, stream, e, idx, out);
    hipLaunchKernelGGL(refine_kernel, dim3(512), dim3(64), 0, stream,
                       x, e, out, worklist, count, maxjobs);
}

// Round 5
// 238.871 us; speedup vs baseline: 7.3087x; 1.1672x over previous
//
#include <hip/hip_runtime.h>

// VQ-VAE quantizer via MFMA: x[B=128,C=256,H=32,W=32] f32, e[K=512,C=256] f32.
// out[b,c,hw] = e[argmin_k ||z - e_k||^2][c].
//
// score_k = ||e_k||^2 - 2 z.e_k. Dot via bf16 MFMA Dekker split (3 terms:
// zh.eh + zl.eh + zh.el, err ~1e-3), each term on its OWN accumulator chain
// (6 chains/wave -> MFMA at issue rate, not latency rate). e-tiles triple-
// buffered in LDS with ONE raw s_barrier + counted vmcnt(4) per iteration
// (loads stay in flight across barriers). Near-ties (gap < EPS) re-resolved
// exactly in fp64 by refine_kernel. Output gather fused into the epilogue.

typedef __attribute__((ext_vector_type(8))) short bf16x8;
typedef __attribute__((ext_vector_type(4))) float f32x4;

constexpr int K_EMB = 512;
constexpr int C_DIM = 256;
constexpr int HW    = 1024;
constexpr float EPS_GAP = 0.02f;

// ws layout (bytes) — same offsets as R4 (idx region now unused)
constexpr size_t WS_EBIAS = 64;                    // f32[512]
constexpr size_t WS_EH    = 4096;                  // bf16 bits [512][256] = 256KB
constexpr size_t WS_EL    = WS_EH + 262144;        // 256KB
constexpr size_t WS_WORK  = WS_EL + 262144 + 524288;

// LDS: 3 x 16KB tile buffers | ebias f32[512] | idx int[128]
constexpr int LDS_TILES = 49152;
constexpr int LDS_EB    = LDS_TILES;           // +2048
constexpr int LDS_IDX   = LDS_TILES + 2048;    // +512

__device__ __forceinline__ unsigned short f2bf(float f) {
    unsigned u = __float_as_uint(f);
    return (unsigned short)((u + 0x7FFFu + ((u >> 16) & 1u)) >> 16);
}

// ---- prep: e -> (eH, eL) bf16 planes + exact ebias, zero job counter ----
__global__ __launch_bounds__(256) void prep_e(const float* __restrict__ e,
                                              unsigned short* __restrict__ eH,
                                              unsigned short* __restrict__ eL,
                                              float* __restrict__ ebias,
                                              int* __restrict__ count) {
    const int k = blockIdx.x, c = threadIdx.x;
    if (k == 0 && c == 0) *count = 0;
    float v = e[(size_t)k * C_DIM + c];
    unsigned short h = f2bf(v);
    float hf = __uint_as_float(((unsigned)h) << 16);
    unsigned short l = f2bf(v - hf);
    eH[(size_t)k * C_DIM + c] = h;
    eL[(size_t)k * C_DIM + c] = l;

    __shared__ double red[256];
    red[c] = (double)v * (double)v;
    __syncthreads();
    for (int s = 128; s > 0; s >>= 1) {
        if (c < s) red[c] += red[c + s];
        __syncthreads();
    }
    if (c == 0) ebias[k] = (float)red[0];
}

// ---- stage one 16-code tile (hi+lo planes, 16KB) into LDS at bufoff ----
// global_load_lds writes lane*16 contiguous from a wave-uniform LDS base;
// bank-conflict swizzle (byte ^= (row&15)<<4) applied on the GLOBAL source
// address (both-sides-or-neither); readers apply the same XOR. (R4-verified.)
__device__ __forceinline__ void stage_tile(char* smem, int bufoff, int nt, int w, int lane,
                                           const unsigned short* eH,
                                           const unsigned short* eL) {
#pragma unroll
    for (int s = 0; s < 4; ++s) {
        int q = w * 4 + s;            // 0..15 across the block
        int plane = q >> 3;           // 0 = hi, 1 = lo
        int ip = q & 7;               // 1KB chunk within plane
        int row = ip * 2 + (lane >> 5);
        int co  = (lane & 31) * 16;   // byte offset within row
        const unsigned short* src = (plane ? eL : eH)
            + ((size_t)(nt * 16 + row)) * C_DIM + ((co ^ ((row & 15) << 4)) >> 1);
        char* dst = smem + bufoff + plane * 8192 + ip * 1024;  // wave-uniform
        __builtin_amdgcn_global_load_lds(
            (const __attribute__((address_space(1))) unsigned int*)src,
            (__attribute__((address_space(3))) unsigned int*)dst, 16, 0, 0);
    }
}

// ---- main: GEMM + in-register argmin + fused output gather ----
__global__ __launch_bounds__(256, 2) void vq_mfma(const float* __restrict__ x,
                                                  const unsigned short* __restrict__ eH,
                                                  const unsigned short* __restrict__ eL,
                                                  const float* __restrict__ ebias,
                                                  const float* __restrict__ e,
                                                  float* __restrict__ out,
                                                  int* __restrict__ count,
                                                  int* __restrict__ worklist,
                                                  int maxjobs) {
    __shared__ __align__(16) char smem[LDS_IDX + 512];
    float* eb_lds = (float*)(smem + LDS_EB);
    int* idx_lds  = (int*)(smem + LDS_IDX);
    const int t = threadIdx.x, lane = t & 63, w = t >> 6;
    const int b = blockIdx.x >> 3;
    const int hw0 = (blockIdx.x & 7) << 7;
    const float* xb = x + (size_t)b * C_DIM * HW;

    // ebias -> LDS (oldest vmem ops; retire during A-build)
    eb_lds[t]       = ebias[t];
    eb_lds[t + 256] = ebias[t + 256];

    // prefetch tiles 0,1 (latency hides under A-build)
    stage_tile(smem, 0,     0, w, lane, eH, eL);
    stage_tile(smem, 16384, 1, w, lane, eH, eL);

    // A fragments: lane holds A[m = lane&15][k = 8*(lane>>4) + j], j=0..7
    bf16x8 Ah[2][8], Al[2][8];
#pragma unroll
    for (int mf = 0; mf < 2; ++mf) {
        const int hw = hw0 + w * 32 + mf * 16 + (lane & 15);
#pragma unroll
        for (int cs = 0; cs < 8; ++cs) {
#pragma unroll
            for (int j = 0; j < 8; ++j) {
                int c = cs * 32 + ((lane >> 4) << 3) + j;
                float v = xb[(size_t)c * HW + hw];
                unsigned short h = f2bf(v);
                float hf = __uint_as_float(((unsigned)h) << 16);
                unsigned short l = f2bf(v - hf);
                Ah[mf][cs][j] = (short)h;
                Al[mf][cs][j] = (short)l;
            }
        }
    }

    float best[8], second[8];
    int bidx[8];
#pragma unroll
    for (int s = 0; s < 8; ++s) { best[s] = 1e30f; second[s] = 1e30f; bidx[s] = 0; }

    // per-lane swizzled LDS read base: row = lane&15 (code), co = (lane>>4)*16
    const int bro = (lane & 15) * 512 + ((((lane >> 4) << 4)) ^ ((lane & 15) << 4));

    // eb_lds ds_writes must be visible across waves after the first barrier
    asm volatile("s_waitcnt lgkmcnt(0)" ::: "memory");

    int cur = 0;
    for (int nt = 0; nt < 32; ++nt) {
        // tile nt's 4 loads complete; tile nt+1's may stay in flight
        if (nt == 31) asm volatile("s_waitcnt vmcnt(0)" ::: "memory");
        else          asm volatile("s_waitcnt vmcnt(4)" ::: "memory");
        __builtin_amdgcn_s_barrier();
        asm volatile("" ::: "memory");

        // stage tile nt+2 into the buffer whose reads finished in iter nt-1
        if (nt < 30) {
            int nb = cur + 32768; if (nb >= LDS_TILES) nb -= LDS_TILES;
            stage_tile(smem, nb, nt + 2, w, lane, eH, eL);
        }

        const char* base = smem + cur;
        f32x4 aH0 = {0,0,0,0}, aH1 = {0,0,0,0};
        f32x4 aA0 = {0,0,0,0}, aA1 = {0,0,0,0};
        f32x4 aB0 = {0,0,0,0}, aB1 = {0,0,0,0};
#pragma unroll
        for (int cs = 0; cs < 8; ++cs) {
            int off = bro ^ (cs << 6);   // XOR-composable: co bits disjoint
            bf16x8 Bh = *reinterpret_cast<const bf16x8*>(base + off);
            bf16x8 Bl = *reinterpret_cast<const bf16x8*>(base + 8192 + off);
            aH0 = __builtin_amdgcn_mfma_f32_16x16x32_bf16(Ah[0][cs], Bh, aH0, 0, 0, 0);
            aH1 = __builtin_amdgcn_mfma_f32_16x16x32_bf16(Ah[1][cs], Bh, aH1, 0, 0, 0);
            aA0 = __builtin_amdgcn_mfma_f32_16x16x32_bf16(Al[0][cs], Bh, aA0, 0, 0, 0);
            aA1 = __builtin_amdgcn_mfma_f32_16x16x32_bf16(Al[1][cs], Bh, aA1, 0, 0, 0);
            aB0 = __builtin_amdgcn_mfma_f32_16x16x32_bf16(Ah[0][cs], Bl, aB0, 0, 0, 0);
            aB1 = __builtin_amdgcn_mfma_f32_16x16x32_bf16(Ah[1][cs], Bl, aB1, 0, 0, 0);
        }

        const int code = nt * 16 + (lane & 15);
        const float eb = eb_lds[code];   // LDS broadcast, no vmcnt traffic
#pragma unroll
        for (int mf = 0; mf < 2; ++mf) {
#pragma unroll
            for (int r = 0; r < 4; ++r) {
                float d = mf ? (aH1[r] + aA1[r] + aB1[r]) : (aH0[r] + aA0[r] + aB0[r]);
                float sc = fmaf(-2.f, d, eb);
                int slot = mf * 4 + r;
                if (sc < best[slot]) { second[slot] = best[slot]; best[slot] = sc; bidx[slot] = code; }
                else second[slot] = fminf(second[slot], sc);
            }
        }

        cur += 16384; if (cur == LDS_TILES) cur = 0;
    }

    // butterfly argmin over the 16 col-lanes (true top-2, first-idx ties)
#pragma unroll
    for (int m = 1; m < 16; m <<= 1) {
#pragma unroll
        for (int s = 0; s < 8; ++s) {
            float ob = __shfl_xor(best[s], m);
            float os = __shfl_xor(second[s], m);
            int   oi = __shfl_xor(bidx[s], m);
            bool take = (ob < best[s]) || (ob == best[s] && oi < bidx[s]);
            float ns = take ? fminf(best[s], os) : fminf(second[s], ob);
            if (take) { best[s] = ob; bidx[s] = oi; }
            second[s] = ns;
        }
    }

    if ((lane & 15) == 0) {
#pragma unroll
        for (int s = 0; s < 8; ++s) {
            int row_local = (s >> 2) * 16 + ((lane >> 4) << 2) + (s & 3);
            int r = w * 32 + row_local;
            idx_lds[r] = bidx[s];
            if (second[s] - best[s] < EPS_GAP) {
                int sl = atomicAdd(count, 1);
                if (sl < maxjobs) worklist[sl] = blockIdx.x * 128 + r;
            }
        }
    }
    __syncthreads();

    // fused gather: out[b,c,hw] = e[idx[j]][c]; float4 gathers from L2,
    // coalesced 256B stores (lanes = consecutive j).
    {
        const int j = t & 127;
        const int half = t >> 7;
        const int code = idx_lds[j];
        const float4* e4 = reinterpret_cast<const float4*>(e);
        float* ob = out + (size_t)b * C_DIM * HW + hw0 + j;
#pragma unroll
        for (int i = 0; i < 32; ++i) {
            int c4 = half * 32 + i;
            float4 v = e4[(size_t)code * 64 + c4];
            ob[(size_t)(c4 * 4 + 0) * HW] = v.x;
            ob[(size_t)(c4 * 4 + 1) * HW] = v.y;
            ob[(size_t)(c4 * 4 + 2) * HW] = v.z;
            ob[(size_t)(c4 * 4 + 3) * HW] = v.w;
        }
    }
}

// ---- refine: exact fp64 argmin for flagged rows, rewrite out row ----
__global__ __launch_bounds__(64) void refine_kernel(const float* __restrict__ x,
                                                    const float* __restrict__ e,
                                                    float* __restrict__ out,
                                                    const int* __restrict__ worklist,
                                                    const int* __restrict__ count,
                                                    int maxjobs) {
    int njobs = *count;
    if (njobs > maxjobs) njobs = maxjobs;
    const int lane = threadIdx.x;

    for (int job = blockIdx.x; job < njobs; job += gridDim.x) {
        const int row = worklist[job];
        const int b = row >> 10;
        const int hw = row & (HW - 1);
        const float* xb = x + (size_t)b * C_DIM * HW + hw;

        double bestd = 1e300;
        int besti = K_EMB;
        for (int k = lane; k < K_EMB; k += 64) {
            const float* er = e + (size_t)k * C_DIM;
            double d = 0.0;
            for (int c = 0; c < C_DIM; ++c) {
                double diff = (double)xb[(size_t)c * HW] - (double)er[c];
                d = fma(diff, diff, d);
            }
            if (d < bestd || (d == bestd && k < besti)) { bestd = d; besti = k; }
        }
        for (int off = 32; off > 0; off >>= 1) {
            double od = __shfl_down(bestd, off);
            int    oi = __shfl_down(besti, off);
            if (od < bestd || (od == bestd && oi < besti)) { bestd = od; besti = oi; }
        }
        besti = __shfl(besti, 0);

        const float4 v = reinterpret_cast<const float4*>(e + (size_t)besti * C_DIM)[lane];
        float* ob = out + (size_t)b * C_DIM * HW + hw;
        ob[(size_t)(lane * 4 + 0) * HW] = v.x;
        ob[(size_t)(lane * 4 + 1) * HW] = v.y;
        ob[(size_t)(lane * 4 + 2) * HW] = v.z;
        ob[(size_t)(lane * 4 + 3) * HW] = v.w;
    }
}

extern "C" void kernel_launch(void* const* d_in, const int* in_sizes, int n_in,
                              void* d_out, int out_size, void* d_ws, size_t ws_size,
                              hipStream_t stream) {
    const float* x = (const float*)d_in[0];
    const float* e = (const float*)d_in[1];
    float* out = (float*)d_out;

    char* ws = (char*)d_ws;
    int* count = (int*)ws;
    float* ebias = (float*)(ws + WS_EBIAS);
    unsigned short* eH = (unsigned short*)(ws + WS_EH);
    unsigned short* eL = (unsigned short*)(ws + WS_EL);
    int* worklist = (int*)(ws + WS_WORK);
    int maxjobs = 0;
    if (ws_size > WS_WORK + 4) {
        size_t avail = (ws_size - WS_WORK) / 4;
        maxjobs = (int)(avail > 65536 ? 65536 : avail);
    }

    const int B = in_sizes[0] / (C_DIM * HW);

    hipLaunchKernelGGL(prep_e, dim3(K_EMB), dim3(256), 0, stream, e, eH, eL, ebias, count);
    hipLaunchKernelGGL(vq_mfma, dim3(B * 8), dim3(256), 0, stream,
                       x, eH, eL, ebias, e, out, count, worklist, maxjobs);
    hipLaunchKernelGGL(refine_kernel, dim3(512), dim3(64), 0, stream,
                       x, e, out, worklist, count, maxjobs);
}